// Round 1
// baseline (791.442 us; speedup 1.0000x reference)
//
#include <hip/hip_runtime.h>
#include <hip/hip_bf16.h>

// ---------------------------------------------------------------------------
// GCN 2-layer forward on MI355X.
// Pipeline per launch (all on `stream`, graph-capture safe):
//   1. memset cnt; histogram in-degree of real edges (int atomics)
//   2. dinv[v] = 1/sqrt(deg_real + 1)          (self-loop included)
//   3. 3-kernel exclusive prefix scan -> rowptr, cursor
//   4. scatter edges into CSR (cols=src, normv=dinv[s]*dinv[d])
//   5. GEMM  h = x @ W1          (fp32 tiled, 64x128 tile, K-chunk 32)
//   6. AGG   out1 = relu(b1 + dinv[v]^2 h[v] + sum normv*h[src])  -> d_out
//   7. GEMM  h = out1 @ W2
//   8. AGG   out  = relu(...)                                     -> d_out
// No float atomics anywhere; CSR rebuild is ~3.2M int atomics (cheap).
// ---------------------------------------------------------------------------

#define DIN 256
#define DH 128

__global__ void count_k(const int* __restrict__ dst, int* __restrict__ cnt, int e) {
    int i = blockIdx.x * 256 + threadIdx.x;
    if (i < e) atomicAdd(&cnt[dst[i]], 1);
}

__global__ void dinv_k(const int* __restrict__ cnt, float* __restrict__ dinv, int n) {
    int i = blockIdx.x * 256 + threadIdx.x;
    if (i < n) dinv[i] = 1.0f / sqrtf((float)(cnt[i] + 1));
}

__global__ void block_sum_k(const int* __restrict__ cnt, int* __restrict__ bsum, int n) {
    __shared__ int s[256];
    int t = threadIdx.x;
    int i = blockIdx.x * 256 + t;
    s[t] = (i < n) ? cnt[i] : 0;
    __syncthreads();
    for (int off = 128; off > 0; off >>= 1) {
        if (t < off) s[t] += s[t + off];
        __syncthreads();
    }
    if (t == 0) bsum[blockIdx.x] = s[0];
}

// single block: exclusive scan of bsum[0..nb) (nb <= 512)
__global__ void scan_bsum_k(int* __restrict__ bsum, int nb) {
    __shared__ int s[512];
    int t = threadIdx.x;
    s[t] = (t < nb) ? bsum[t] : 0;
    __syncthreads();
    for (int off = 1; off < 512; off <<= 1) {
        int x = (t >= off) ? s[t - off] : 0;
        __syncthreads();
        s[t] += x;
        __syncthreads();
    }
    if (t < nb) bsum[t] = (t == 0) ? 0 : s[t - 1];
}

__global__ void scan_write_k(const int* __restrict__ cnt, const int* __restrict__ bsum,
                             int* __restrict__ rowptr, int* __restrict__ cursor, int n) {
    __shared__ int s[256];
    int t = threadIdx.x;
    int i = blockIdx.x * 256 + t;
    int c = (i < n) ? cnt[i] : 0;
    s[t] = c;
    __syncthreads();
    for (int off = 1; off < 256; off <<= 1) {
        int x = (t >= off) ? s[t - off] : 0;
        __syncthreads();
        s[t] += x;
        __syncthreads();
    }
    int excl = s[t] - c + bsum[blockIdx.x];
    if (i < n) {
        rowptr[i] = excl;
        cursor[i] = excl;
        if (i == n - 1) rowptr[n] = excl + c;  // == E
    }
}

__global__ void scatter_k(const int* __restrict__ src, const int* __restrict__ dst,
                          const float* __restrict__ dinv, int* __restrict__ cursor,
                          int* __restrict__ cols, float* __restrict__ normv, int e) {
    int i = blockIdx.x * 256 + threadIdx.x;
    if (i < e) {
        int s = src[i], d = dst[i];
        int pos = atomicAdd(&cursor[d], 1);
        cols[pos] = s;
        normv[pos] = dinv[s] * dinv[d];
    }
}

// C[M,128] = A[M,K] @ B[K,128], fp32. Tile: 64 rows x 128 cols, K-chunk 32.
// 256 threads; each computes 8 rows x 4 cols. A staged transposed in LDS so the
// inner loop is 2x ds_read_b128 (A) + 1x ds_read_b128 (B) per 32 FMA.
__global__ __launch_bounds__(256) void gemm_f32(const float* __restrict__ A,
                                                const float* __restrict__ B,
                                                float* __restrict__ C, int M, int K) {
    __shared__ __align__(16) float As[32][68];   // [k][row], pad 68 (16B-multiple stride)
    __shared__ __align__(16) float Bs[32][128];  // [k][col]
    int t = threadIdx.x;
    int tx = t & 31;      // col group: cols 4*tx .. 4*tx+3
    int ty = t >> 5;      // row group: rows 8*ty .. 8*ty+7
    int row0 = blockIdx.x * 64;
    float acc[8][4] = {};

    for (int k0 = 0; k0 < K; k0 += 32) {
        // stage A tile: 64 rows x 32 k  (512 float4 loads, transposed store)
        for (int f = t; f < 512; f += 256) {
            int r = f >> 3, kq = f & 7;
            int grow = row0 + r;
            float4 v = make_float4(0.f, 0.f, 0.f, 0.f);
            if (grow < M) v = *(const float4*)(A + (size_t)grow * K + k0 + kq * 4);
            As[kq * 4 + 0][r] = v.x;
            As[kq * 4 + 1][r] = v.y;
            As[kq * 4 + 2][r] = v.z;
            As[kq * 4 + 3][r] = v.w;
        }
        // stage B tile: 32 k x 128 cols (1024 float4)
        for (int f = t; f < 1024; f += 256) {
            int kk = f >> 5, c4 = f & 31;
            *(float4*)&Bs[kk][c4 * 4] = *(const float4*)(B + (size_t)(k0 + kk) * 128 + c4 * 4);
        }
        __syncthreads();
#pragma unroll
        for (int kk = 0; kk < 32; ++kk) {
            float4 b4 = *(const float4*)&Bs[kk][tx * 4];
            float4 a40 = *(const float4*)&As[kk][ty * 8];
            float4 a41 = *(const float4*)&As[kk][ty * 8 + 4];
            float ar[8] = {a40.x, a40.y, a40.z, a40.w, a41.x, a41.y, a41.z, a41.w};
#pragma unroll
            for (int r = 0; r < 8; ++r) {
                acc[r][0] = fmaf(ar[r], b4.x, acc[r][0]);
                acc[r][1] = fmaf(ar[r], b4.y, acc[r][1]);
                acc[r][2] = fmaf(ar[r], b4.z, acc[r][2]);
                acc[r][3] = fmaf(ar[r], b4.w, acc[r][3]);
            }
        }
        __syncthreads();
    }
#pragma unroll
    for (int r = 0; r < 8; ++r) {
        int grow = row0 + ty * 8 + r;
        if (grow < M) {
            float4 v = make_float4(acc[r][0], acc[r][1], acc[r][2], acc[r][3]);
            *(float4*)(C + (size_t)grow * 128 + tx * 4) = v;
        }
    }
}

// One wave per node; lane f handles features f and f+64.
__global__ __launch_bounds__(256) void agg_k(const float* __restrict__ h,
                                             const int* __restrict__ rowptr,
                                             const int* __restrict__ cols,
                                             const float* __restrict__ normv,
                                             const float* __restrict__ dinv,
                                             const float* __restrict__ bias,
                                             float* __restrict__ out, int n) {
    int v = blockIdx.x * 4 + (threadIdx.x >> 6);
    int lane = threadIdx.x & 63;
    if (v >= n) return;
    float dv = dinv[v];
    const float* hv = h + (size_t)v * DH;
    float self = dv * dv;
    float a0 = self * hv[lane];
    float a1 = self * hv[lane + 64];
    int beg = rowptr[v], end = rowptr[v + 1];
    for (int i = beg; i < end; ++i) {
        int s = cols[i];
        float w = normv[i];
        const float* hs = h + (size_t)s * DH;
        a0 = fmaf(w, hs[lane], a0);
        a1 = fmaf(w, hs[lane + 64], a1);
    }
    out[(size_t)v * DH + lane] = fmaxf(a0 + bias[lane], 0.f);
    out[(size_t)v * DH + lane + 64] = fmaxf(a1 + bias[lane + 64], 0.f);
}

static inline size_t align_up(size_t x, size_t a) { return (x + a - 1) & ~(a - 1); }

extern "C" void kernel_launch(void* const* d_in, const int* in_sizes, int n_in,
                              void* d_out, int out_size, void* d_ws, size_t ws_size,
                              hipStream_t stream) {
    const float* x  = (const float*)d_in[0];
    const int*   ei = (const int*)d_in[1];
    const float* W1 = (const float*)d_in[2];
    const float* b1 = (const float*)d_in[3];
    const float* W2 = (const float*)d_in[4];
    const float* b2 = (const float*)d_in[5];

    const int N = in_sizes[0] / DIN;   // 100000
    const int E = in_sizes[1] / 2;     // 1600000
    const int* src = ei;
    const int* dst = ei + E;

    // workspace partition
    char* base = (char*)d_ws;
    size_t off = 0;
    int* cnt = (int*)(base + off);        off = align_up(off + (size_t)N * 4, 256);
    int* rowptr = (int*)(base + off);     off = align_up(off + (size_t)(N + 1) * 4, 256);
    int* cursor = (int*)(base + off);     off = align_up(off + (size_t)N * 4, 256);
    float* dinv = (float*)(base + off);   off = align_up(off + (size_t)N * 4, 256);
    int* bsum = (int*)(base + off);       off = align_up(off + 512 * 4, 256);
    int* cols = (int*)(base + off);       off = align_up(off + (size_t)E * 4, 256);
    float* normv = (float*)(base + off);  off = align_up(off + (size_t)E * 4, 256);
    float* h = (float*)(base + off);      off = align_up(off + (size_t)N * DH * 4, 256);

    float* out = (float*)d_out;

    const int NB = (N + 255) / 256;

    hipMemsetAsync(cnt, 0, (size_t)N * sizeof(int), stream);
    count_k<<<(E + 255) / 256, 256, 0, stream>>>(dst, cnt, E);
    dinv_k<<<(N + 255) / 256, 256, 0, stream>>>(cnt, dinv, N);
    block_sum_k<<<NB, 256, 0, stream>>>(cnt, bsum, N);
    scan_bsum_k<<<1, 512, 0, stream>>>(bsum, NB);
    scan_write_k<<<NB, 256, 0, stream>>>(cnt, bsum, rowptr, cursor, N);
    scatter_k<<<(E + 255) / 256, 256, 0, stream>>>(src, dst, dinv, cursor, cols, normv, E);

    // layer 1
    gemm_f32<<<(N + 63) / 64, 256, 0, stream>>>(x, W1, h, N, DIN);
    agg_k<<<(N + 3) / 4, 256, 0, stream>>>(h, rowptr, cols, normv, dinv, b1, out, N);
    // layer 2
    gemm_f32<<<(N + 63) / 64, 256, 0, stream>>>(out, W2, h, N, DH);
    agg_k<<<(N + 3) / 4, 256, 0, stream>>>(h, rowptr, cols, normv, dinv, b2, out, N);
}

// Round 2
// 749.658 us; speedup vs baseline: 1.0557x; 1.0557x over previous
//
#include <hip/hip_runtime.h>
#include <hip/hip_bf16.h>

// ---------------------------------------------------------------------------
// GCN 2-layer forward on MI355X.
// Pipeline per launch (all on `stream`, graph-capture safe):
//   1. memset cnt; histogram in-degree of real edges (int atomics)
//   2. dinv[v] = 1/sqrt(deg_real + 1)          (self-loop included)
//   3. 3-kernel exclusive prefix scan -> rowptr, cursor
//   4. scatter edges into CSR (cols=src, normv=dinv[s]*dinv[d])
//   5. GEMM  h = x @ W1          (fp32 tiled, 128x128 tile, 8x8/thread)
//   6. AGG   out1 = relu(b1 + dinv[v]^2 h[v] + sum normv*h[src])  -> d_out
//   7. GEMM  h = out1 @ W2
//   8. AGG   out  = relu(...)                                     -> d_out
// agg_k: 1 wave/node, float2/lane (512B row in one instr), unroll-4 gathers
// for 4x memory-level parallelism (R1 counters: latency-bound at 15% VALU).
// ---------------------------------------------------------------------------

#define DIN 256
#define DH 128

__global__ void count_k(const int* __restrict__ dst, int* __restrict__ cnt, int e) {
    int i = blockIdx.x * 256 + threadIdx.x;
    if (i < e) atomicAdd(&cnt[dst[i]], 1);
}

__global__ void dinv_k(const int* __restrict__ cnt, float* __restrict__ dinv, int n) {
    int i = blockIdx.x * 256 + threadIdx.x;
    if (i < n) dinv[i] = 1.0f / sqrtf((float)(cnt[i] + 1));
}

__global__ void block_sum_k(const int* __restrict__ cnt, int* __restrict__ bsum, int n) {
    __shared__ int s[256];
    int t = threadIdx.x;
    int i = blockIdx.x * 256 + t;
    s[t] = (i < n) ? cnt[i] : 0;
    __syncthreads();
    for (int off = 128; off > 0; off >>= 1) {
        if (t < off) s[t] += s[t + off];
        __syncthreads();
    }
    if (t == 0) bsum[blockIdx.x] = s[0];
}

// single block: exclusive scan of bsum[0..nb) (nb <= 512)
__global__ void scan_bsum_k(int* __restrict__ bsum, int nb) {
    __shared__ int s[512];
    int t = threadIdx.x;
    s[t] = (t < nb) ? bsum[t] : 0;
    __syncthreads();
    for (int off = 1; off < 512; off <<= 1) {
        int x = (t >= off) ? s[t - off] : 0;
        __syncthreads();
        s[t] += x;
        __syncthreads();
    }
    if (t < nb) bsum[t] = (t == 0) ? 0 : s[t - 1];
}

__global__ void scan_write_k(const int* __restrict__ cnt, const int* __restrict__ bsum,
                             int* __restrict__ rowptr, int* __restrict__ cursor, int n) {
    __shared__ int s[256];
    int t = threadIdx.x;
    int i = blockIdx.x * 256 + t;
    int c = (i < n) ? cnt[i] : 0;
    s[t] = c;
    __syncthreads();
    for (int off = 1; off < 256; off <<= 1) {
        int x = (t >= off) ? s[t - off] : 0;
        __syncthreads();
        s[t] += x;
        __syncthreads();
    }
    int excl = s[t] - c + bsum[blockIdx.x];
    if (i < n) {
        rowptr[i] = excl;
        cursor[i] = excl;
        if (i == n - 1) rowptr[n] = excl + c;  // == E
    }
}

__global__ void scatter_k(const int* __restrict__ src, const int* __restrict__ dst,
                          const float* __restrict__ dinv, int* __restrict__ cursor,
                          int* __restrict__ cols, float* __restrict__ normv, int e) {
    int i = blockIdx.x * 256 + threadIdx.x;
    if (i < e) {
        int s = src[i], d = dst[i];
        int pos = atomicAdd(&cursor[d], 1);
        cols[pos] = s;
        normv[pos] = dinv[s] * dinv[d];
    }
}

// C[M,128] = A[M,K] @ B[K,128], fp32. Tile: 128 rows x 128 cols, K-chunk 32.
// 256 threads; each computes 8 rows x 8 cols (64 FMA per 64B LDS -> LDS-balanced).
__global__ __launch_bounds__(256) void gemm_f32(const float* __restrict__ A,
                                                const float* __restrict__ B,
                                                float* __restrict__ C, int M, int K) {
    __shared__ __align__(16) float As[32][132];  // [k][row], pad to 132
    __shared__ __align__(16) float Bs[32][128];  // [k][col]
    int t = threadIdx.x;
    int tx = t & 15;      // col group: cols 8*tx .. 8*tx+7
    int ty = t >> 4;      // row group: rows 8*ty .. 8*ty+7
    int row0 = blockIdx.x * 128;
    float acc[8][8] = {};

    for (int k0 = 0; k0 < K; k0 += 32) {
        // stage A tile: 128 rows x 32 k (1024 float4, transposed store)
        for (int f = t; f < 1024; f += 256) {
            int r = f >> 3, kq = f & 7;
            int grow = row0 + r;
            float4 v = make_float4(0.f, 0.f, 0.f, 0.f);
            if (grow < M) v = *(const float4*)(A + (size_t)grow * K + k0 + kq * 4);
            As[kq * 4 + 0][r] = v.x;
            As[kq * 4 + 1][r] = v.y;
            As[kq * 4 + 2][r] = v.z;
            As[kq * 4 + 3][r] = v.w;
        }
        // stage B tile: 32 k x 128 cols (1024 float4)
        for (int f = t; f < 1024; f += 256) {
            int kk = f >> 5, c4 = f & 31;
            *(float4*)&Bs[kk][c4 * 4] = *(const float4*)(B + (size_t)(k0 + kk) * 128 + c4 * 4);
        }
        __syncthreads();
#pragma unroll
        for (int kk = 0; kk < 32; ++kk) {
            float4 a40 = *(const float4*)&As[kk][ty * 8];
            float4 a41 = *(const float4*)&As[kk][ty * 8 + 4];
            float4 b40 = *(const float4*)&Bs[kk][tx * 8];
            float4 b41 = *(const float4*)&Bs[kk][tx * 8 + 4];
            float ar[8] = {a40.x, a40.y, a40.z, a40.w, a41.x, a41.y, a41.z, a41.w};
            float br[8] = {b40.x, b40.y, b40.z, b40.w, b41.x, b41.y, b41.z, b41.w};
#pragma unroll
            for (int r = 0; r < 8; ++r)
#pragma unroll
                for (int c = 0; c < 8; ++c)
                    acc[r][c] = fmaf(ar[r], br[c], acc[r][c]);
        }
        __syncthreads();
    }
#pragma unroll
    for (int r = 0; r < 8; ++r) {
        int grow = row0 + ty * 8 + r;
        if (grow < M) {
            *(float4*)(C + (size_t)grow * 128 + tx * 8) =
                make_float4(acc[r][0], acc[r][1], acc[r][2], acc[r][3]);
            *(float4*)(C + (size_t)grow * 128 + tx * 8 + 4) =
                make_float4(acc[r][4], acc[r][5], acc[r][6], acc[r][7]);
        }
    }
}

// One wave per node; lane f handles features 2f, 2f+1 (one dwordx2 = full row).
// Unroll-4 over edges: 4 independent row-gathers in flight per wave.
__global__ __launch_bounds__(256) void agg_k(const float* __restrict__ h,
                                             const int* __restrict__ rowptr,
                                             const int* __restrict__ cols,
                                             const float* __restrict__ normv,
                                             const float* __restrict__ dinv,
                                             const float* __restrict__ bias,
                                             float* __restrict__ out, int n) {
    int v = blockIdx.x * 4 + (threadIdx.x >> 6);
    int lane = threadIdx.x & 63;
    if (v >= n) return;
    const float2* __restrict__ h2 = (const float2*)h;  // row stride 64
    float dv = dinv[v];
    float self = dv * dv;
    float2 hv = h2[(size_t)v * 64 + lane];
    float ax = self * hv.x, ay = self * hv.y;
    int i = rowptr[v], end = rowptr[v + 1];
    for (; i + 4 <= end; i += 4) {
        int s0 = cols[i], s1 = cols[i + 1], s2 = cols[i + 2], s3 = cols[i + 3];
        float w0 = normv[i], w1 = normv[i + 1], w2 = normv[i + 2], w3 = normv[i + 3];
        float2 v0 = h2[(size_t)s0 * 64 + lane];
        float2 v1 = h2[(size_t)s1 * 64 + lane];
        float2 v2 = h2[(size_t)s2 * 64 + lane];
        float2 v3 = h2[(size_t)s3 * 64 + lane];
        ax = fmaf(w0, v0.x, ax); ay = fmaf(w0, v0.y, ay);
        ax = fmaf(w1, v1.x, ax); ay = fmaf(w1, v1.y, ay);
        ax = fmaf(w2, v2.x, ax); ay = fmaf(w2, v2.y, ay);
        ax = fmaf(w3, v3.x, ax); ay = fmaf(w3, v3.y, ay);
    }
    for (; i < end; ++i) {
        int s = cols[i];
        float w = normv[i];
        float2 vv = h2[(size_t)s * 64 + lane];
        ax = fmaf(w, vv.x, ax); ay = fmaf(w, vv.y, ay);
    }
    const float2* __restrict__ b2 = (const float2*)bias;
    float2 bb = b2[lane];
    float2 o;
    o.x = fmaxf(ax + bb.x, 0.f);
    o.y = fmaxf(ay + bb.y, 0.f);
    ((float2*)out)[(size_t)v * 64 + lane] = o;
}

static inline size_t align_up(size_t x, size_t a) { return (x + a - 1) & ~(a - 1); }

extern "C" void kernel_launch(void* const* d_in, const int* in_sizes, int n_in,
                              void* d_out, int out_size, void* d_ws, size_t ws_size,
                              hipStream_t stream) {
    const float* x  = (const float*)d_in[0];
    const int*   ei = (const int*)d_in[1];
    const float* W1 = (const float*)d_in[2];
    const float* b1 = (const float*)d_in[3];
    const float* W2 = (const float*)d_in[4];
    const float* b2 = (const float*)d_in[5];

    const int N = in_sizes[0] / DIN;   // 100000
    const int E = in_sizes[1] / 2;     // 1600000
    const int* src = ei;
    const int* dst = ei + E;

    // workspace partition
    char* base = (char*)d_ws;
    size_t off = 0;
    int* cnt = (int*)(base + off);        off = align_up(off + (size_t)N * 4, 256);
    int* rowptr = (int*)(base + off);     off = align_up(off + (size_t)(N + 1) * 4, 256);
    int* cursor = (int*)(base + off);     off = align_up(off + (size_t)N * 4, 256);
    float* dinv = (float*)(base + off);   off = align_up(off + (size_t)N * 4, 256);
    int* bsum = (int*)(base + off);       off = align_up(off + 512 * 4, 256);
    int* cols = (int*)(base + off);       off = align_up(off + (size_t)E * 4, 256);
    float* normv = (float*)(base + off);  off = align_up(off + (size_t)E * 4, 256);
    float* h = (float*)(base + off);      off = align_up(off + (size_t)N * DH * 4, 256);

    float* out = (float*)d_out;

    const int NB = (N + 255) / 256;

    hipMemsetAsync(cnt, 0, (size_t)N * sizeof(int), stream);
    count_k<<<(E + 255) / 256, 256, 0, stream>>>(dst, cnt, E);
    dinv_k<<<(N + 255) / 256, 256, 0, stream>>>(cnt, dinv, N);
    block_sum_k<<<NB, 256, 0, stream>>>(cnt, bsum, N);
    scan_bsum_k<<<1, 512, 0, stream>>>(bsum, NB);
    scan_write_k<<<NB, 256, 0, stream>>>(cnt, bsum, rowptr, cursor, N);
    scatter_k<<<(E + 255) / 256, 256, 0, stream>>>(src, dst, dinv, cursor, cols, normv, E);

    // layer 1
    gemm_f32<<<(N + 127) / 128, 256, 0, stream>>>(x, W1, h, N, DIN);
    agg_k<<<(N + 3) / 4, 256, 0, stream>>>(h, rowptr, cols, normv, dinv, b1, out, N);
    // layer 2
    gemm_f32<<<(N + 127) / 128, 256, 0, stream>>>(out, W2, h, N, DH);
    agg_k<<<(N + 3) / 4, 256, 0, stream>>>(h, rowptr, cols, normv, dinv, b2, out, N);
}

// Round 3
// 521.404 us; speedup vs baseline: 1.5179x; 1.4378x over previous
//
#include <hip/hip_runtime.h>
#include <hip/hip_bf16.h>

// ---------------------------------------------------------------------------
// GCN 2-layer forward on MI355X (gfx950).
// Pipeline (all on `stream`, graph-capture safe):
//   prep: degree histogram -> dinv -> prefix-scan -> CSR scatter (einfo=int2)
//   wt_k: W1,W2 -> bf16 transposed Wt[n][k] (once per launch)
//   L1: gemm_mfma<A=f32>(x, Wt1) -> h_bf16 ; agg<out=bf16> -> a1_bf16
//   L2: gemm_mfma<A=bf16>(a1, Wt2) -> h_bf16 ; agg<out=f32> -> d_out
// GEMM: MFMA 16x16x32 bf16, block=128 rows x 128 cols, wave=32 rows.
//   B staged in LDS fragment-major ((ks*8+ct)*1024 + lane*16) => all LDS
//   traffic is stride-1 b128 (conflict-free, m136). A-rows are wave-private
//   => loaded straight from global (16 rows x 128B contiguous per instr).
// agg: 1 wave/node, bf16 row = 1 dword/lane, unroll-4 gathers, fp32 accum.
// ---------------------------------------------------------------------------

#define DIN 256
#define DH 128

typedef __attribute__((ext_vector_type(8))) short short8;
typedef __attribute__((ext_vector_type(4))) float f32x4;

__device__ __forceinline__ unsigned short f2bf(float f) {
    union { float f; unsigned int i; } c;
    c.f = f;
    unsigned int r = c.i + 0x7FFFu + ((c.i >> 16) & 1u);  // RNE
    return (unsigned short)(r >> 16);
}
__device__ __forceinline__ float bf_lo(unsigned int u) {
    union { unsigned int i; float f; } c;
    c.i = u << 16;
    return c.f;
}
__device__ __forceinline__ float bf_hi(unsigned int u) {
    union { unsigned int i; float f; } c;
    c.i = u & 0xFFFF0000u;
    return c.f;
}

// ---------------- prep ----------------
__global__ void count_k(const int* __restrict__ dst, int* __restrict__ cnt, int e) {
    int i = blockIdx.x * 256 + threadIdx.x;
    if (i < e) atomicAdd(&cnt[dst[i]], 1);
}

__global__ void dinv_k(const int* __restrict__ cnt, float* __restrict__ dinv, int n) {
    int i = blockIdx.x * 256 + threadIdx.x;
    if (i < n) dinv[i] = 1.0f / sqrtf((float)(cnt[i] + 1));
}

__global__ void block_sum_k(const int* __restrict__ cnt, int* __restrict__ bsum, int n) {
    __shared__ int s[256];
    int t = threadIdx.x;
    int i = blockIdx.x * 256 + t;
    s[t] = (i < n) ? cnt[i] : 0;
    __syncthreads();
    for (int off = 128; off > 0; off >>= 1) {
        if (t < off) s[t] += s[t + off];
        __syncthreads();
    }
    if (t == 0) bsum[blockIdx.x] = s[0];
}

__global__ void scan_bsum_k(int* __restrict__ bsum, int nb) {
    __shared__ int s[512];
    int t = threadIdx.x;
    s[t] = (t < nb) ? bsum[t] : 0;
    __syncthreads();
    for (int off = 1; off < 512; off <<= 1) {
        int x = (t >= off) ? s[t - off] : 0;
        __syncthreads();
        s[t] += x;
        __syncthreads();
    }
    if (t < nb) bsum[t] = (t == 0) ? 0 : s[t - 1];
}

__global__ void scan_write_k(const int* __restrict__ cnt, const int* __restrict__ bsum,
                             int* __restrict__ rowptr, int* __restrict__ cursor, int n) {
    __shared__ int s[256];
    int t = threadIdx.x;
    int i = blockIdx.x * 256 + t;
    int c = (i < n) ? cnt[i] : 0;
    s[t] = c;
    __syncthreads();
    for (int off = 1; off < 256; off <<= 1) {
        int x = (t >= off) ? s[t - off] : 0;
        __syncthreads();
        s[t] += x;
        __syncthreads();
    }
    int excl = s[t] - c + bsum[blockIdx.x];
    if (i < n) {
        rowptr[i] = excl;
        cursor[i] = excl;
        if (i == n - 1) rowptr[n] = excl + c;
    }
}

__global__ void scatter_k(const int* __restrict__ src, const int* __restrict__ dst,
                          const float* __restrict__ dinv, int* __restrict__ cursor,
                          int2* __restrict__ einfo, int e) {
    int i = blockIdx.x * 256 + threadIdx.x;
    if (i < e) {
        int s = src[i], d = dst[i];
        int pos = atomicAdd(&cursor[d], 1);
        float w = dinv[s] * dinv[d];
        einfo[pos] = make_int2(s, __float_as_int(w));
    }
}

// W [K][128] f32 -> Wt [128][K] bf16
__global__ void wt_k(const float* __restrict__ W, unsigned short* __restrict__ Wt, int K) {
    int i = blockIdx.x * 256 + threadIdx.x;
    if (i < K * 128) {
        int k = i >> 7, n = i & 127;
        Wt[(size_t)n * K + k] = f2bf(W[i]);
    }
}

// ---------------- GEMM (MFMA bf16) ----------------
// C[M,128] = A[M,K] @ Wt^T ; Wt is [128][K] bf16. Output Hb [M][128] bf16.
// Block: 128 rows; wave w: rows w*32..w*32+31 (2 row-tiles), all 8 col-tiles.
template <bool A_BF16>
__global__ __launch_bounds__(256) void gemm_mfma(const void* __restrict__ Av,
                                                 const unsigned short* __restrict__ Wt,
                                                 unsigned short* __restrict__ Hb,
                                                 int M, int K) {
    __shared__ unsigned short Bt[16384];  // 32 KB: 32 frag-groups x 1024 B
    const int t = threadIdx.x;
    const int w = t >> 6;
    const int lane = t & 63;
    const int l15 = lane & 15;
    const int quad = lane >> 4;
    const int row0 = blockIdx.x * 128 + w * 32;

    const float* Af = (const float*)Av;
    const unsigned short* Ab = (const unsigned short*)Av;

    f32x4 acc[2][8];
#pragma unroll
    for (int rt = 0; rt < 2; ++rt)
#pragma unroll
        for (int ct = 0; ct < 8; ++ct)
#pragma unroll
            for (int j = 0; j < 4; ++j) acc[rt][ct][j] = 0.0f;

    for (int kc = 0; kc < K; kc += 128) {
        if (kc) __syncthreads();
        // stage B chunk, fragment-major: group fg=(ks*8+ct), lane-contiguous 16B
#pragma unroll
        for (int i = 0; i < 8; ++i) {
            int fg = w * 8 + i;            // ks = fg>>3, ct = fg&7
            int ks = fg >> 3, ct = fg & 7;
            int nn = ct * 16 + l15;
            int gk = ks * 32 + quad * 8;
            *(short8*)&Bt[fg * 512 + lane * 8] =
                *(const short8*)(Wt + (size_t)nn * K + kc + gk);
        }
        __syncthreads();
#pragma unroll
        for (int ks = 0; ks < 4; ++ks) {
            int kk = ks * 32 + quad * 8;
            short8 af[2];
#pragma unroll
            for (int rt = 0; rt < 2; ++rt) {
                int row = row0 + rt * 16 + l15;
                if (row < M) {
                    if (A_BF16) {
                        af[rt] = *(const short8*)(Ab + (size_t)row * K + kc + kk);
                    } else {
                        const float* p = Af + (size_t)row * K + kc + kk;
                        float4 x0 = *(const float4*)p;
                        float4 x1 = *(const float4*)(p + 4);
                        af[rt][0] = (short)f2bf(x0.x);
                        af[rt][1] = (short)f2bf(x0.y);
                        af[rt][2] = (short)f2bf(x0.z);
                        af[rt][3] = (short)f2bf(x0.w);
                        af[rt][4] = (short)f2bf(x1.x);
                        af[rt][5] = (short)f2bf(x1.y);
                        af[rt][6] = (short)f2bf(x1.z);
                        af[rt][7] = (short)f2bf(x1.w);
                    }
                } else {
#pragma unroll
                    for (int j = 0; j < 8; ++j) af[rt][j] = 0;
                }
            }
#pragma unroll
            for (int ct = 0; ct < 8; ++ct) {
                short8 bfr = *(const short8*)&Bt[(ks * 8 + ct) * 512 + lane * 8];
                acc[0][ct] = __builtin_amdgcn_mfma_f32_16x16x32_bf16(af[0], bfr, acc[0][ct], 0, 0, 0);
                acc[1][ct] = __builtin_amdgcn_mfma_f32_16x16x32_bf16(af[1], bfr, acc[1][ct], 0, 0, 0);
            }
        }
    }
    // epilogue: D[row=quad*4+reg][col=l15] per tile -> bf16 store
#pragma unroll
    for (int rt = 0; rt < 2; ++rt)
#pragma unroll
        for (int r = 0; r < 4; ++r) {
            int row = row0 + rt * 16 + quad * 4 + r;
            if (row < M) {
                unsigned short* o = Hb + (size_t)row * 128 + l15;
#pragma unroll
                for (int ct = 0; ct < 8; ++ct) o[ct * 16] = f2bf(acc[rt][ct][r]);
            }
        }
}

// ---------------- aggregation ----------------
// One wave per node; lane holds features 2*lane, 2*lane+1 (one dword of bf16x2).
template <bool OUT_BF16>
__global__ __launch_bounds__(256) void agg_k(const unsigned short* __restrict__ Hb,
                                             const int* __restrict__ rowptr,
                                             const int2* __restrict__ einfo,
                                             const float* __restrict__ dinv,
                                             const float* __restrict__ bias,
                                             void* __restrict__ out, int n) {
    int v = blockIdx.x * 4 + (threadIdx.x >> 6);
    int lane = threadIdx.x & 63;
    if (v >= n) return;
    const unsigned int* __restrict__ H = (const unsigned int*)Hb;  // row stride 64 dwords
    float dv = dinv[v];
    float self = dv * dv;
    unsigned int hv = H[(size_t)v * 64 + lane];
    float ax = self * bf_lo(hv), ay = self * bf_hi(hv);
    int i = rowptr[v], end = rowptr[v + 1];
    for (; i + 4 <= end; i += 4) {
        int2 e0 = einfo[i], e1 = einfo[i + 1], e2 = einfo[i + 2], e3 = einfo[i + 3];
        unsigned int v0 = H[(size_t)e0.x * 64 + lane];
        unsigned int v1 = H[(size_t)e1.x * 64 + lane];
        unsigned int v2 = H[(size_t)e2.x * 64 + lane];
        unsigned int v3 = H[(size_t)e3.x * 64 + lane];
        float w0 = __int_as_float(e0.y), w1 = __int_as_float(e1.y);
        float w2 = __int_as_float(e2.y), w3 = __int_as_float(e3.y);
        ax = fmaf(w0, bf_lo(v0), ax); ay = fmaf(w0, bf_hi(v0), ay);
        ax = fmaf(w1, bf_lo(v1), ax); ay = fmaf(w1, bf_hi(v1), ay);
        ax = fmaf(w2, bf_lo(v2), ax); ay = fmaf(w2, bf_hi(v2), ay);
        ax = fmaf(w3, bf_lo(v3), ax); ay = fmaf(w3, bf_hi(v3), ay);
    }
    for (; i < end; ++i) {
        int2 e = einfo[i];
        unsigned int vv = H[(size_t)e.x * 64 + lane];
        float w = __int_as_float(e.y);
        ax = fmaf(w, bf_lo(vv), ax); ay = fmaf(w, bf_hi(vv), ay);
    }
    float2 bb = ((const float2*)bias)[lane];
    float ox = fmaxf(ax + bb.x, 0.f);
    float oy = fmaxf(ay + bb.y, 0.f);
    if (OUT_BF16) {
        unsigned int p = (unsigned int)f2bf(ox) | ((unsigned int)f2bf(oy) << 16);
        ((unsigned int*)out)[(size_t)v * 64 + lane] = p;
    } else {
        ((float2*)out)[(size_t)v * 64 + lane] = make_float2(ox, oy);
    }
}

static inline size_t align_up(size_t x, size_t a) { return (x + a - 1) & ~(a - 1); }

extern "C" void kernel_launch(void* const* d_in, const int* in_sizes, int n_in,
                              void* d_out, int out_size, void* d_ws, size_t ws_size,
                              hipStream_t stream) {
    const float* x  = (const float*)d_in[0];
    const int*   ei = (const int*)d_in[1];
    const float* W1 = (const float*)d_in[2];
    const float* b1 = (const float*)d_in[3];
    const float* W2 = (const float*)d_in[4];
    const float* b2 = (const float*)d_in[5];

    const int N = in_sizes[0] / DIN;   // 100000
    const int E = in_sizes[1] / 2;     // 1600000
    const int* src = ei;
    const int* dst = ei + E;

    // workspace partition
    char* base = (char*)d_ws;
    size_t off = 0;
    int* cnt = (int*)(base + off);          off = align_up(off + (size_t)N * 4, 256);
    int* rowptr = (int*)(base + off);       off = align_up(off + (size_t)(N + 1) * 4, 256);
    int* cursor = (int*)(base + off);       off = align_up(off + (size_t)N * 4, 256);
    float* dinv = (float*)(base + off);     off = align_up(off + (size_t)N * 4, 256);
    int* bsum = (int*)(base + off);         off = align_up(off + 512 * 4, 256);
    int2* einfo = (int2*)(base + off);      off = align_up(off + (size_t)E * 8, 256);
    unsigned short* Wt1 = (unsigned short*)(base + off); off = align_up(off + (size_t)128 * 256 * 2, 256);
    unsigned short* Wt2 = (unsigned short*)(base + off); off = align_up(off + (size_t)128 * 128 * 2, 256);
    unsigned short* hb  = (unsigned short*)(base + off); off = align_up(off + (size_t)N * 128 * 2, 256);
    unsigned short* a1b = (unsigned short*)(base + off); off = align_up(off + (size_t)N * 128 * 2, 256);

    float* out = (float*)d_out;
    const int NB = (N + 255) / 256;

    hipMemsetAsync(cnt, 0, (size_t)N * sizeof(int), stream);
    count_k<<<(E + 255) / 256, 256, 0, stream>>>(dst, cnt, E);
    dinv_k<<<(N + 255) / 256, 256, 0, stream>>>(cnt, dinv, N);
    block_sum_k<<<NB, 256, 0, stream>>>(cnt, bsum, N);
    scan_bsum_k<<<1, 512, 0, stream>>>(bsum, NB);
    scan_write_k<<<NB, 256, 0, stream>>>(cnt, bsum, rowptr, cursor, N);
    scatter_k<<<(E + 255) / 256, 256, 0, stream>>>(src, dst, dinv, cursor, einfo, E);
    wt_k<<<(256 * 128 + 255) / 256, 256, 0, stream>>>(W1, Wt1, 256);
    wt_k<<<(128 * 128 + 255) / 256, 256, 0, stream>>>(W2, Wt2, 128);

    const int GB = (N + 127) / 128;
    // layer 1
    gemm_mfma<false><<<GB, 256, 0, stream>>>(x, Wt1, hb, N, DIN);
    agg_k<true><<<(N + 3) / 4, 256, 0, stream>>>(hb, rowptr, einfo, dinv, b1, a1b, N);
    // layer 2
    gemm_mfma<true><<<GB, 256, 0, stream>>>(a1b, Wt2, hb, N, DH);
    agg_k<false><<<(N + 3) / 4, 256, 0, stream>>>(hb, rowptr, einfo, dinv, b2, out, N);
}